// Round 8
// baseline (347.754 us; speedup 1.0000x reference)
//
#include <hip/hip_runtime.h>
#include <hip/hip_bf16.h>
#include <math.h>

#define BB 2
#define SS 2048
#define DMM 1024
#define HH 16
#define HDD 64
#define NGLOB 32

typedef __attribute__((ext_vector_type(8))) short short8;
typedef __attribute__((ext_vector_type(4))) float float4v;

__device__ __forceinline__ short f2bf(float f) {
    union { float f; unsigned u; } x; x.f = f;
    unsigned r = (x.u + 0x7fffu + ((x.u >> 16) & 1u)) >> 16;  // RNE
    return (short)r;
}

// ---------------- setup: parallel dedup'd global list (order irrelevant) ----------------
__global__ void setup_globals(const int* __restrict__ gidx, int* __restrict__ g,
                              int* __restrict__ glist, int* __restrict__ gcount) {
    int t = threadIdx.x;
    for (int i = t; i < SS; i += 256) g[i] = 0;
    if (t == 0) *gcount = 0;
    __syncthreads();
    if (t < NGLOB) {
        int j = gidx[t];
        if (j >= 0 && j < SS) g[j] = 1;
    }
    __syncthreads();
    for (int j = t; j < SS; j += 256) {
        if (g[j]) {
            int p = atomicAdd(gcount, 1);
            glist[p] = j;
        }
    }
}

// ---------------- convert 4 weight matrices fp32 -> bf16 (once) ----------------
__global__ __launch_bounds__(256)
void convert_w(const float* __restrict__ w0, const float* __restrict__ w1,
               const float* __restrict__ w2, const float* __restrict__ w3,
               short* __restrict__ out) {
    int z = blockIdx.y;
    const float* src = (z == 0) ? w0 : (z == 1) ? w1 : (z == 2) ? w2 : w3;
    short* dst = out + (size_t)z * (DMM * DMM);
    int i = (blockIdx.x * 256 + threadIdx.x) * 8;
    float4 a = *(const float4*)(src + i);
    float4 b = *(const float4*)(src + i + 4);
    short8 s;
    s[0]=f2bf(a.x); s[1]=f2bf(a.y); s[2]=f2bf(a.z); s[3]=f2bf(a.w);
    s[4]=f2bf(b.x); s[5]=f2bf(b.y); s[6]=f2bf(b.z); s[7]=f2bf(b.w);
    *(short8*)(dst + i) = s;
}

// ---------------- MFMA bf16 GEMM: C = A * W^T + bias ----------------
// A: [M,K] fp32 (ABF=0) or bf16 (ABF=1); W: [N,K] bf16 (pre-converted); bias fp32.
// Tile 64(M) x 128(N), BK=32, 256 threads, 1D grid 512 with XCD-panel swizzle:
// XCD x owns m-blocks [8x, 8x+8) so A-panel (2MB fp32) + W (2MB bf16) fit 4MB L2.
template<int ABF, int OBF, int HEADSPLIT>
__global__ __launch_bounds__(256)
void gemm_mfma(const void* __restrict__ Ap, const short* __restrict__ W,
               const float* __restrict__ bias, void* __restrict__ outp) {
    __shared__ short As[64 * 40];
    __shared__ short Ws[128 * 40];

    int t = threadIdx.x;
    int bid = blockIdx.x;
    int xcd = bid & 7, loc = bid >> 3;        // 8 XCDs round-robin on linear id
    int nblk = loc & 7, mloc = loc >> 3;      // per-XCD: 8 m-blocks x 8 n-blocks
    int m0 = (xcd * 8 + mloc) * 64;
    int n0 = nblk * 128;

    int lane = t & 63, w = t >> 6;
    int quad = lane >> 4, col = lane & 15;
    int arow0 = (w >> 1) * 32;
    int ncol0 = (w & 1) * 64;

    float4v acc[2][4];
    #pragma unroll
    for (int i = 0; i < 2; i++)
        #pragma unroll
        for (int j = 0; j < 4; j++) acc[i][j] = (float4v){0, 0, 0, 0};

    int srow = t >> 1;
    int scol = (t & 1) * 16;

    for (int k0 = 0; k0 < DMM; k0 += 32) {
        __syncthreads();
        {   // W tile: bf16 direct copy, packed b128 stores
            const short* p = W + (size_t)(n0 + srow) * DMM + k0 + scol;
            short8 s0 = *(const short8*)p;
            short8 s1 = *(const short8*)(p + 8);
            *(short8*)&Ws[srow * 40 + scol]     = s0;
            *(short8*)&Ws[srow * 40 + scol + 8] = s1;
        }
        if (t < 128) {
            if (ABF) {
                const short* p = (const short*)Ap + (size_t)(m0 + srow) * DMM + k0 + scol;
                short8 s0 = *(const short8*)p;
                short8 s1 = *(const short8*)(p + 8);
                *(short8*)&As[srow * 40 + scol]     = s0;
                *(short8*)&As[srow * 40 + scol + 8] = s1;
            } else {
                const float* p = (const float*)Ap + (size_t)(m0 + srow) * DMM + k0 + scol;
                float4 f0 = *(const float4*)p;
                float4 f1 = *(const float4*)(p + 4);
                float4 f2 = *(const float4*)(p + 8);
                float4 f3 = *(const float4*)(p + 12);
                short8 s0, s1;
                s0[0]=f2bf(f0.x); s0[1]=f2bf(f0.y); s0[2]=f2bf(f0.z); s0[3]=f2bf(f0.w);
                s0[4]=f2bf(f1.x); s0[5]=f2bf(f1.y); s0[6]=f2bf(f1.z); s0[7]=f2bf(f1.w);
                s1[0]=f2bf(f2.x); s1[1]=f2bf(f2.y); s1[2]=f2bf(f2.z); s1[3]=f2bf(f2.w);
                s1[4]=f2bf(f3.x); s1[5]=f2bf(f3.y); s1[6]=f2bf(f3.z); s1[7]=f2bf(f3.w);
                *(short8*)&As[srow * 40 + scol]     = s0;
                *(short8*)&As[srow * 40 + scol + 8] = s1;
            }
        }
        __syncthreads();

        short8 aF[2], bF[4];
        #pragma unroll
        for (int i = 0; i < 2; i++)
            aF[i] = *(short8*)&As[(arow0 + 16 * i + col) * 40 + quad * 8];
        #pragma unroll
        for (int j = 0; j < 4; j++)
            bF[j] = *(short8*)&Ws[(ncol0 + 16 * j + col) * 40 + quad * 8];

        #pragma unroll
        for (int i = 0; i < 2; i++)
            #pragma unroll
            for (int j = 0; j < 4; j++)
                acc[i][j] = __builtin_amdgcn_mfma_f32_16x16x32_bf16(aF[i], bF[j], acc[i][j], 0, 0, 0);
    }

    #pragma unroll
    for (int i = 0; i < 2; i++) {
        #pragma unroll
        for (int j = 0; j < 4; j++) {
            int n = n0 + ncol0 + 16 * j + col;
            float bn = bias[n];
            #pragma unroll
            for (int r = 0; r < 4; r++) {
                int m = m0 + arow0 + 16 * i + quad * 4 + r;
                float val = acc[i][j][r] + bn;
                size_t idx;
                if (HEADSPLIT) {
                    int b = m >> 11;
                    int s = m & 2047;
                    int h = n >> 6;
                    int hd = n & 63;
                    idx = (((size_t)b * HH + h) * SS + s) * HDD + hd;
                } else {
                    idx = (size_t)m * DMM + n;
                }
                if (OBF) ((short*)outp)[idx] = f2bf(val);
                else     ((float*)outp)[idx] = val;
            }
        }
    }
}

// ---------------- banded MFMA attention (parity-split flash; no-max softmax) ----------------
__global__ __launch_bounds__(256)
void band_attn(const short* __restrict__ qh, const short* __restrict__ kh,
               const short* __restrict__ vh, const int* __restrict__ glist,
               const int* __restrict__ gcount, short* __restrict__ ao) {
    __shared__ short Qs[64 * 72];
    __shared__ short Ks[32 * 72];
    __shared__ short Vt[64 * 40];
    __shared__ short Ps[4 * 16 * 40];
    __shared__ int   gjs[32];

    int t = threadIdx.x;
    int qt = blockIdx.x, h = blockIdx.y, z = blockIdx.z;
    int b = z >> 1, p = z & 1;
    int qq0 = qt * 64;
    int nG = *gcount;

    const short* Qb = qh + ((size_t)(b * HH + h) * SS) * HDD;
    const short* Kb = kh + ((size_t)(b * HH + h) * SS) * HDD;
    const short* Vb = vh + ((size_t)(b * HH + h) * SS) * HDD;

    int row8 = t >> 3;
    int dim8 = (t & 7) * 8;

    #pragma unroll
    for (int rr = 0; rr < 2; rr++) {
        int row = rr * 32 + row8;
        int i = 2 * (qq0 + row) + p;
        short8 qv = *(const short8*)(Qb + (size_t)i * HDD + dim8);
        *(short8*)&Qs[row * 72 + dim8] = qv;
    }
    if (t < 32) gjs[t] = (t < nG) ? glist[t] : -1000000;
    __syncthreads();

    int lane = t & 63, w = t >> 6;
    int quad = lane >> 4, col = lane & 15;

    short8 qf0 = *(short8*)&Qs[(16 * w + col) * 72 + quad * 8];
    short8 qf1 = *(short8*)&Qs[(16 * w + col) * 72 + 32 + quad * 8];

    float4v O0 = {0,0,0,0}, O1 = {0,0,0,0}, O2 = {0,0,0,0}, O3 = {0,0,0,0};
    float lst[4] = {0.f, 0.f, 0.f, 0.f};

    for (int c = 0; c < 19; c++) {
        __syncthreads();
        int ch0 = qq0 - 256 + c * 32;
        int srow;
        if (c < 18) srow = 2 * (ch0 + row8) + p;
        else        srow = (row8 < nG) ? gjs[row8] : 0;
        srow = srow < 0 ? 0 : (srow > SS - 1 ? SS - 1 : srow);
        short8 kv = *(const short8*)(Kb + (size_t)srow * HDD + dim8);
        short8 vv = *(const short8*)(Vb + (size_t)srow * HDD + dim8);
        *(short8*)&Ks[row8 * 72 + dim8] = kv;
        #pragma unroll
        for (int j = 0; j < 8; j++) Vt[(dim8 + j) * 40 + row8] = vv[j];
        __syncthreads();

        short8 kA0 = *(short8*)&Ks[col * 72 + quad * 8];
        short8 kA1 = *(short8*)&Ks[col * 72 + 32 + quad * 8];
        short8 kB0 = *(short8*)&Ks[(16 + col) * 72 + quad * 8];
        short8 kB1 = *(short8*)&Ks[(16 + col) * 72 + 32 + quad * 8];
        float4v sA = {0,0,0,0}, sB = {0,0,0,0};
        sA = __builtin_amdgcn_mfma_f32_16x16x32_bf16(qf0, kA0, sA, 0, 0, 0);
        sA = __builtin_amdgcn_mfma_f32_16x16x32_bf16(qf1, kA1, sA, 0, 0, 0);
        sB = __builtin_amdgcn_mfma_f32_16x16x32_bf16(qf0, kB0, sB, 0, 0, 0);
        sB = __builtin_amdgcn_mfma_f32_16x16x32_bf16(qf1, kB1, sB, 0, 0, 0);

        #pragma unroll
        for (int r = 0; r < 4; r++) {
            int q  = 16 * w + quad * 4 + r;
            int qq = qq0 + q;
            bool vA, vB;
            if (c < 18) {
                int jA = ch0 + col, jB = jA + 16;
                int dA = jA - qq; dA = dA < 0 ? -dA : dA;
                int dB = jB - qq; dB = dB < 0 ? -dB : dB;
                vA = (jA >= 0) && (jA < 1024) && (dA <= 256);
                vB = (jB >= 0) && (jB < 1024) && (dB <= 256);
            } else {
                int i = 2 * qq + p;
                int jA = gjs[col], jB = gjs[col + 16];
                int dA = jA - i, dB = jB - i;
                int aA = dA < 0 ? -dA : dA;
                int aB = dB < 0 ? -dB : dB;
                vA = (jA >= 0) && !((aA <= 512) && ((dA & 1) == 0));
                vB = (jB >= 0) && !((aB <= 512) && ((dB & 1) == 0));
            }
            float pa = vA ? __expf(sA[r] * 0.125f) : 0.f;
            float pb = vB ? __expf(sB[r] * 0.125f) : 0.f;
            lst[r] += pa + pb;
            Ps[(w * 16 + quad * 4 + r) * 40 + col]      = f2bf(pa);
            Ps[(w * 16 + quad * 4 + r) * 40 + col + 16] = f2bf(pb);
        }
        asm volatile("s_waitcnt lgkmcnt(0)" ::: "memory");

        short8 pf  = *(short8*)&Ps[(w * 16 + col) * 40 + quad * 8];
        short8 vf0 = *(short8*)&Vt[(col) * 40 + quad * 8];
        short8 vf1 = *(short8*)&Vt[(16 + col) * 40 + quad * 8];
        short8 vf2 = *(short8*)&Vt[(32 + col) * 40 + quad * 8];
        short8 vf3 = *(short8*)&Vt[(48 + col) * 40 + quad * 8];
        O0 = __builtin_amdgcn_mfma_f32_16x16x32_bf16(pf, vf0, O0, 0, 0, 0);
        O1 = __builtin_amdgcn_mfma_f32_16x16x32_bf16(pf, vf1, O1, 0, 0, 0);
        O2 = __builtin_amdgcn_mfma_f32_16x16x32_bf16(pf, vf2, O2, 0, 0, 0);
        O3 = __builtin_amdgcn_mfma_f32_16x16x32_bf16(pf, vf3, O3, 0, 0, 0);
    }

    #pragma unroll
    for (int r = 0; r < 4; r++) {
        float l = lst[r];
        #pragma unroll
        for (int mk = 1; mk < 16; mk <<= 1) l += __shfl_xor(l, mk);
        float inv = 1.0f / l;
        int q = 16 * w + quad * 4 + r;
        int i = 2 * (qq0 + q) + p;
        short* dst = ao + ((size_t)b * SS + i) * DMM + h * HDD;
        dst[col]      = f2bf(O0[r] * inv);
        dst[col + 16] = f2bf(O1[r] * inv);
        dst[col + 32] = f2bf(O2[r] * inv);
        dst[col + 48] = f2bf(O3[r] * inv);
    }
}

// ---------------- global rows: split-K MFMA partials (no-max softmax) ----------------
__global__ __launch_bounds__(256)
void global_part(const short* __restrict__ qh, const short* __restrict__ kh,
                 const short* __restrict__ vh, const int* __restrict__ glist,
                 const int* __restrict__ gcount,
                 float* __restrict__ pl, float* __restrict__ pO) {
    __shared__ short Qs[32 * 72];
    __shared__ short Ks[2][32 * 72];
    __shared__ short Vt[2][64 * 40];
    __shared__ short Ps[4 * 16 * 40];

    int t = threadIdx.x;
    int s = blockIdx.x, h = blockIdx.y, b = blockIdx.z;
    int nG = *gcount;

    const short* Qb = qh + ((size_t)(b * HH + h) * SS) * HDD;
    const short* Kb = kh + ((size_t)(b * HH + h) * SS) * HDD;
    const short* Vb = vh + ((size_t)(b * HH + h) * SS) * HDD;

    int row8 = t >> 3, dim8 = (t & 7) * 8;
    {
        int cq = row8 < nG ? row8 : 0;
        int src = glist[cq];
        short8 qv = *(const short8*)(Qb + (size_t)src * HDD + dim8);
        *(short8*)&Qs[row8 * 72 + dim8] = qv;
    }
    __syncthreads();

    int lane = t & 63, w = t >> 6;
    int quad = lane >> 4, col = lane & 15;
    int g = w >> 1, qt = w & 1;

    short8 qf0 = *(short8*)&Qs[(qt * 16 + col) * 72 + quad * 8];
    short8 qf1 = *(short8*)&Qs[(qt * 16 + col) * 72 + 32 + quad * 8];

    float4v O0 = {0,0,0,0}, O1 = {0,0,0,0}, O2 = {0,0,0,0}, O3 = {0,0,0,0};
    float lst[4] = {0.f, 0.f, 0.f, 0.f};

    int js0 = s * 256;
    for (int it = 0; it < 4; it++) {
        __syncthreads();
        int r64 = t >> 2, dimb = (t & 3) * 16;
        int j = js0 + it * 64 + r64;
        const short* kp = Kb + (size_t)j * HDD + dimb;
        const short* vp = Vb + (size_t)j * HDD + dimb;
        short8 k0 = *(const short8*)kp, k1 = *(const short8*)(kp + 8);
        short8 v0 = *(const short8*)vp, v1 = *(const short8*)(vp + 8);
        int half = r64 >> 5, r32 = r64 & 31;
        *(short8*)&Ks[half][r32 * 72 + dimb]     = k0;
        *(short8*)&Ks[half][r32 * 72 + dimb + 8] = k1;
        #pragma unroll
        for (int u = 0; u < 8; u++) Vt[half][(dimb + u) * 40 + r32]     = v0[u];
        #pragma unroll
        for (int u = 0; u < 8; u++) Vt[half][(dimb + 8 + u) * 40 + r32] = v1[u];
        __syncthreads();

        short8 kA0 = *(short8*)&Ks[g][col * 72 + quad * 8];
        short8 kA1 = *(short8*)&Ks[g][col * 72 + 32 + quad * 8];
        short8 kB0 = *(short8*)&Ks[g][(16 + col) * 72 + quad * 8];
        short8 kB1 = *(short8*)&Ks[g][(16 + col) * 72 + 32 + quad * 8];
        float4v sA = {0,0,0,0}, sB = {0,0,0,0};
        sA = __builtin_amdgcn_mfma_f32_16x16x32_bf16(qf0, kA0, sA, 0, 0, 0);
        sA = __builtin_amdgcn_mfma_f32_16x16x32_bf16(qf1, kA1, sA, 0, 0, 0);
        sB = __builtin_amdgcn_mfma_f32_16x16x32_bf16(qf0, kB0, sB, 0, 0, 0);
        sB = __builtin_amdgcn_mfma_f32_16x16x32_bf16(qf1, kB1, sB, 0, 0, 0);

        #pragma unroll
        for (int r = 0; r < 4; r++) {
            float pa = __expf(sA[r] * 0.125f);
            float pb = __expf(sB[r] * 0.125f);
            lst[r] += pa + pb;
            Ps[(w * 16 + quad * 4 + r) * 40 + col]      = f2bf(pa);
            Ps[(w * 16 + quad * 4 + r) * 40 + col + 16] = f2bf(pb);
        }
        asm volatile("s_waitcnt lgkmcnt(0)" ::: "memory");

        short8 pf  = *(short8*)&Ps[(w * 16 + col) * 40 + quad * 8];
        short8 vf0 = *(short8*)&Vt[g][(col) * 40 + quad * 8];
        short8 vf1 = *(short8*)&Vt[g][(16 + col) * 40 + quad * 8];
        short8 vf2 = *(short8*)&Vt[g][(32 + col) * 40 + quad * 8];
        short8 vf3 = *(short8*)&Vt[g][(48 + col) * 40 + quad * 8];
        O0 = __builtin_amdgcn_mfma_f32_16x16x32_bf16(pf, vf0, O0, 0, 0, 0);
        O1 = __builtin_amdgcn_mfma_f32_16x16x32_bf16(pf, vf1, O1, 0, 0, 0);
        O2 = __builtin_amdgcn_mfma_f32_16x16x32_bf16(pf, vf2, O2, 0, 0, 0);
        O3 = __builtin_amdgcn_mfma_f32_16x16x32_bf16(pf, vf3, O3, 0, 0, 0);
    }

    int sp = s * 2 + g;
    size_t base = ((size_t)(b * HH + h) * 16 + sp) * 32;
    #pragma unroll
    for (int r = 0; r < 4; r++) {
        float l = lst[r];
        #pragma unroll
        for (int mk = 1; mk < 16; mk <<= 1) l += __shfl_xor(l, mk);
        int q = qt * 16 + quad * 4 + r;
        if (col == 0) pl[base + q] = l;
        float* Od = pO + (base + q) * 64;
        Od[col]      = O0[r];
        Od[col + 16] = O1[r];
        Od[col + 32] = O2[r];
        Od[col + 48] = O3[r];
    }
}

// ---------------- merge 16 partials per (b,h): plain sums ----------------
__global__ __launch_bounds__(256)
void global_merge(const float* __restrict__ pl, const float* __restrict__ pO,
                  const int* __restrict__ glist, const int* __restrict__ gcount,
                  short* __restrict__ ao) {
    int h = blockIdx.x, b = blockIdx.y;
    int t = threadIdx.x;
    int d = t & 63, qg = t >> 6;
    int nG = *gcount;
    size_t bh = ((size_t)(b * HH + h) * 16) * 32;

    for (int q = qg; q < nG; q += 4) {
        float L = 0.f, acc = 0.f;
        #pragma unroll
        for (int sp = 0; sp < 16; sp++) {
            L   += pl[bh + sp * 32 + q];
            acc += pO[(bh + sp * 32 + q) * 64 + d];
        }
        int i = glist[q];
        ao[((size_t)b * SS + i) * DMM + h * HDD + d] = f2bf(acc / L);
    }
}

extern "C" void kernel_launch(void* const* d_in, const int* in_sizes, int n_in,
                              void* d_out, int out_size, void* d_ws, size_t ws_size,
                              hipStream_t stream) {
    const float* q  = (const float*)d_in[0];
    const float* k  = (const float*)d_in[1];
    const float* v  = (const float*)d_in[2];
    const float* Wq = (const float*)d_in[3];
    const float* Wk = (const float*)d_in[4];
    const float* Wv = (const float*)d_in[5];
    const float* Wo = (const float*)d_in[6];
    const float* bq = (const float*)d_in[7];
    const float* bk = (const float*)d_in[8];
    const float* bv = (const float*)d_in[9];
    const float* bo = (const float*)d_in[10];
    const int* gidx = (const int*)d_in[11];
    float* out = (float*)d_out;

    // ws: 32KB hdr | qh,kh,vh,ao bf16 8MB ea | pl 64KB | pO 4MB | Wbf16 2MB x4
    const size_t NE = (size_t)BB * SS * DMM;
    const size_t WE = (size_t)DMM * DMM;
    int*   g      = (int*)d_ws;
    int*   glist  = g + SS;
    int*   gcount = glist + SS;
    short* qh     = (short*)((char*)d_ws + 32768);
    short* kh     = qh + NE;
    short* vh     = kh + NE;
    short* ao     = vh + NE;
    float* pl     = (float*)(ao + NE);
    float* pO     = pl + 16384;
    short* wbf    = (short*)(pO + 16384 * 64);
    short* wq     = wbf;
    short* wk     = wbf + WE;
    short* wv     = wbf + 2 * WE;
    short* wo     = wbf + 3 * WE;

    setup_globals<<<1, 256, 0, stream>>>(gidx, g, glist, gcount);

    dim3 gc(512, 4);
    convert_w<<<gc, 256, 0, stream>>>(Wq, Wk, Wv, Wo, wbf);

    gemm_mfma<0,1,1><<<512, 256, 0, stream>>>(q, wq, bq, qh);
    gemm_mfma<0,1,1><<<512, 256, 0, stream>>>(k, wk, bk, kh);
    gemm_mfma<0,1,1><<<512, 256, 0, stream>>>(v, wv, bv, vh);

    dim3 ga(16, HH, BB * 2);
    band_attn<<<ga, 256, 0, stream>>>(qh, kh, vh, glist, gcount, ao);

    dim3 gp(8, HH, BB);
    global_part<<<gp, 256, 0, stream>>>(qh, kh, vh, glist, gcount, pl, pO);

    dim3 gm(HH, BB);
    global_merge<<<gm, 256, 0, stream>>>(pl, pO, glist, gcount, ao);

    gemm_mfma<1,0,0><<<512, 256, 0, stream>>>(ao, wo, bo, out);
}

// Round 9
// 249.920 us; speedup vs baseline: 1.3915x; 1.3915x over previous
//
#include <hip/hip_runtime.h>
#include <hip/hip_bf16.h>
#include <math.h>

#define BB 2
#define SS 2048
#define DMM 1024
#define HH 16
#define HDD 64
#define NGLOB 32

typedef __attribute__((ext_vector_type(8))) short short8;
typedef __attribute__((ext_vector_type(4))) float float4v;

__device__ __forceinline__ short f2bf(float f) {
    union { float f; unsigned u; } x; x.f = f;
    unsigned r = (x.u + 0x7fffu + ((x.u >> 16) & 1u)) >> 16;  // RNE
    return (short)r;
}

// ---------------- setup: parallel dedup'd global list (order irrelevant) ----------------
__global__ void setup_globals(const int* __restrict__ gidx, int* __restrict__ g,
                              int* __restrict__ glist, int* __restrict__ gcount) {
    int t = threadIdx.x;
    for (int i = t; i < SS; i += 256) g[i] = 0;
    if (t == 0) *gcount = 0;
    __syncthreads();
    if (t < NGLOB) {
        int j = gidx[t];
        if (j >= 0 && j < SS) g[j] = 1;
    }
    __syncthreads();
    for (int j = t; j < SS; j += 256) {
        if (g[j]) {
            int p = atomicAdd(gcount, 1);
            glist[p] = j;
        }
    }
}

// ---------------- convert 4 weight matrices fp32 -> bf16 (once) ----------------
__global__ __launch_bounds__(256)
void convert_w(const float* __restrict__ w0, const float* __restrict__ w1,
               const float* __restrict__ w2, const float* __restrict__ w3,
               short* __restrict__ out) {
    int z = blockIdx.y;
    const float* src = (z == 0) ? w0 : (z == 1) ? w1 : (z == 2) ? w2 : w3;
    short* dst = out + (size_t)z * (DMM * DMM);
    int i = (blockIdx.x * 256 + threadIdx.x) * 8;
    float4 a = *(const float4*)(src + i);
    float4 b = *(const float4*)(src + i + 4);
    short8 s;
    s[0]=f2bf(a.x); s[1]=f2bf(a.y); s[2]=f2bf(a.z); s[3]=f2bf(a.w);
    s[4]=f2bf(b.x); s[5]=f2bf(b.y); s[6]=f2bf(b.z); s[7]=f2bf(b.w);
    *(short8*)(dst + i) = s;
}

// ---------------- MFMA bf16 GEMM, pipelined: C = A * W^T + bias ----------------
// Tile 64(M) x 128(N), BK=64, 16 K-iters, 256 threads, grid (512, nz).
// Register-staged prefetch: next tile's global loads issued before MFMA so the
// s_waitcnt lands at the NEXT iteration's ds_write (latency overlapped).
// LDS: row stride 64 shorts, 16B chunk c of row r stored at slot c^(r&7)
// -> frag b128 reads/writes hit all 32 banks (conflict floor).
// z (blockIdx.y) selects one of up to 3 independent GEMMs (batched QKV).
template<int ABF, int OBF, int HEADSPLIT>
__global__ __launch_bounds__(256)
void gemm_mfma(const void* __restrict__ A0, const void* __restrict__ A1,
               const void* __restrict__ A2, const short* __restrict__ Wbase,
               const float* __restrict__ b0, const float* __restrict__ b1,
               const float* __restrict__ b2,
               void* __restrict__ O0p, void* __restrict__ O1p, void* __restrict__ O2p) {
    __shared__ short As[64 * 64];    // 8 KB
    __shared__ short Ws[128 * 64];   // 16 KB

    int t = threadIdx.x;
    int z = blockIdx.y;
    const void* Ap    = (z == 0) ? A0 : (z == 1) ? A1 : A2;
    const short* W    = Wbase + (size_t)z * DMM * DMM;
    const float* bias = (z == 0) ? b0 : (z == 1) ? b1 : b2;
    void* outp        = (z == 0) ? O0p : (z == 1) ? O1p : O2p;

    int bid = blockIdx.x;
    int xcd = bid & 7, loc = bid >> 3;        // XCD round-robin
    int nblk = loc & 7, mloc = loc >> 3;      // n fast: A m-panel reused by 8 n-blocks
    int m0 = (xcd * 8 + mloc) * 64;
    int n0 = nblk * 128;

    int lane = t & 63, w = t >> 6;
    int quad = lane >> 4, col = lane & 15;
    int arow0 = (w >> 1) * 32;
    int ncol0 = (w & 1) * 64;

    float4v acc[2][4];
    #pragma unroll
    for (int i = 0; i < 2; i++)
        #pragma unroll
        for (int j = 0; j < 4; j++) acc[i][j] = (float4v){0, 0, 0, 0};

    // staging geometry (BK=64)
    int srowA = t >> 2;           // 0..63, 2 chunks (32B) per thread
    int ca0   = (t & 3) * 2;      // chunk pair
    int srowW = t >> 1;           // 0..127, 4 chunks (64B) per thread
    int cw0   = (t & 1) * 4;

    const short* Abf = (const short*)Ap;
    const float* Afp = (const float*)Ap;

    // staged registers
    float4 a4[4];                 // fp32 A path
    short8 ab[2];                 // bf16 A path
    short8 wr[4];

    // ---- prologue: load tile 0
    {
        const short* wp = W + (size_t)(n0 + srowW) * DMM + cw0 * 8;
        #pragma unroll
        for (int u = 0; u < 4; u++) wr[u] = *(const short8*)(wp + u * 8);
        if (ABF) {
            const short* p = Abf + (size_t)(m0 + srowA) * DMM + ca0 * 8;
            ab[0] = *(const short8*)p;
            ab[1] = *(const short8*)(p + 8);
        } else {
            const float* p = Afp + (size_t)(m0 + srowA) * DMM + ca0 * 8;
            #pragma unroll
            for (int u = 0; u < 4; u++) a4[u] = *(const float4*)(p + u * 4);
        }
    }

    for (int it = 0; it < 16; it++) {
        __syncthreads();   // prior iteration's frag readers done
        // ---- commit staged tile to LDS (swizzled)
        #pragma unroll
        for (int u = 0; u < 4; u++) {
            int c = cw0 + u;
            *(short8*)&Ws[srowW * 64 + ((c ^ (srowW & 7)) * 8)] = wr[u];
        }
        if (ABF) {
            *(short8*)&As[srowA * 64 + (((ca0    ) ^ (srowA & 7)) * 8)] = ab[0];
            *(short8*)&As[srowA * 64 + (((ca0 + 1) ^ (srowA & 7)) * 8)] = ab[1];
        } else {
            short8 s0, s1;
            s0[0]=f2bf(a4[0].x); s0[1]=f2bf(a4[0].y); s0[2]=f2bf(a4[0].z); s0[3]=f2bf(a4[0].w);
            s0[4]=f2bf(a4[1].x); s0[5]=f2bf(a4[1].y); s0[6]=f2bf(a4[1].z); s0[7]=f2bf(a4[1].w);
            s1[0]=f2bf(a4[2].x); s1[1]=f2bf(a4[2].y); s1[2]=f2bf(a4[2].z); s1[3]=f2bf(a4[2].w);
            s1[4]=f2bf(a4[3].x); s1[5]=f2bf(a4[3].y); s1[6]=f2bf(a4[3].z); s1[7]=f2bf(a4[3].w);
            *(short8*)&As[srowA * 64 + (((ca0    ) ^ (srowA & 7)) * 8)] = s0;
            *(short8*)&As[srowA * 64 + (((ca0 + 1) ^ (srowA & 7)) * 8)] = s1;
        }
        __syncthreads();

        // ---- prefetch next tile (loads stay in flight through MFMA below)
        if (it < 15) {
            int k0 = (it + 1) * 64;
            const short* wp = W + (size_t)(n0 + srowW) * DMM + k0 + cw0 * 8;
            #pragma unroll
            for (int u = 0; u < 4; u++) wr[u] = *(const short8*)(wp + u * 8);
            if (ABF) {
                const short* p = Abf + (size_t)(m0 + srowA) * DMM + k0 + ca0 * 8;
                ab[0] = *(const short8*)p;
                ab[1] = *(const short8*)(p + 8);
            } else {
                const float* p = Afp + (size_t)(m0 + srowA) * DMM + k0 + ca0 * 8;
                #pragma unroll
                for (int u = 0; u < 4; u++) a4[u] = *(const float4*)(p + u * 4);
            }
        }

        // ---- frag reads + MFMA, per k-half (limits register pressure)
        #pragma unroll
        for (int kh = 0; kh < 2; kh++) {
            short8 aF[2], bF[4];
            #pragma unroll
            for (int i = 0; i < 2; i++) {
                int row = arow0 + 16 * i + col;
                int c = kh * 4 + quad;
                aF[i] = *(short8*)&As[row * 64 + ((c ^ (row & 7)) * 8)];
            }
            #pragma unroll
            for (int j = 0; j < 4; j++) {
                int row = ncol0 + 16 * j + col;
                int c = kh * 4 + quad;
                bF[j] = *(short8*)&Ws[row * 64 + ((c ^ (row & 7)) * 8)];
            }
            #pragma unroll
            for (int i = 0; i < 2; i++)
                #pragma unroll
                for (int j = 0; j < 4; j++)
                    acc[i][j] = __builtin_amdgcn_mfma_f32_16x16x32_bf16(aF[i], bF[j], acc[i][j], 0, 0, 0);
        }
    }

    #pragma unroll
    for (int i = 0; i < 2; i++) {
        #pragma unroll
        for (int j = 0; j < 4; j++) {
            int n = n0 + ncol0 + 16 * j + col;
            float bn = bias[n];
            #pragma unroll
            for (int r = 0; r < 4; r++) {
                int m = m0 + arow0 + 16 * i + quad * 4 + r;
                float val = acc[i][j][r] + bn;
                size_t idx;
                if (HEADSPLIT) {
                    int b = m >> 11;
                    int s = m & 2047;
                    int h = n >> 6;
                    int hd = n & 63;
                    idx = (((size_t)b * HH + h) * SS + s) * HDD + hd;
                } else {
                    idx = (size_t)m * DMM + n;
                }
                if (OBF) ((short*)outp)[idx] = f2bf(val);
                else     ((float*)outp)[idx] = val;
            }
        }
    }
}

// ---------------- banded MFMA attention (parity-split flash; no-max softmax) ----------------
__global__ __launch_bounds__(256)
void band_attn(const short* __restrict__ qh, const short* __restrict__ kh,
               const short* __restrict__ vh, const int* __restrict__ glist,
               const int* __restrict__ gcount, short* __restrict__ ao) {
    __shared__ short Qs[64 * 72];
    __shared__ short Ks[32 * 72];
    __shared__ short Vt[64 * 40];
    __shared__ short Ps[4 * 16 * 40];
    __shared__ int   gjs[32];

    int t = threadIdx.x;
    int qt = blockIdx.x, h = blockIdx.y, z = blockIdx.z;
    int b = z >> 1, p = z & 1;
    int qq0 = qt * 64;
    int nG = *gcount;

    const short* Qb = qh + ((size_t)(b * HH + h) * SS) * HDD;
    const short* Kb = kh + ((size_t)(b * HH + h) * SS) * HDD;
    const short* Vb = vh + ((size_t)(b * HH + h) * SS) * HDD;

    int row8 = t >> 3;
    int dim8 = (t & 7) * 8;

    #pragma unroll
    for (int rr = 0; rr < 2; rr++) {
        int row = rr * 32 + row8;
        int i = 2 * (qq0 + row) + p;
        short8 qv = *(const short8*)(Qb + (size_t)i * HDD + dim8);
        *(short8*)&Qs[row * 72 + dim8] = qv;
    }
    if (t < 32) gjs[t] = (t < nG) ? glist[t] : -1000000;
    __syncthreads();

    int lane = t & 63, w = t >> 6;
    int quad = lane >> 4, col = lane & 15;

    short8 qf0 = *(short8*)&Qs[(16 * w + col) * 72 + quad * 8];
    short8 qf1 = *(short8*)&Qs[(16 * w + col) * 72 + 32 + quad * 8];

    float4v O0 = {0,0,0,0}, O1 = {0,0,0,0}, O2 = {0,0,0,0}, O3 = {0,0,0,0};
    float lst[4] = {0.f, 0.f, 0.f, 0.f};

    for (int c = 0; c < 19; c++) {
        __syncthreads();
        int ch0 = qq0 - 256 + c * 32;
        int srow;
        if (c < 18) srow = 2 * (ch0 + row8) + p;
        else        srow = (row8 < nG) ? gjs[row8] : 0;
        srow = srow < 0 ? 0 : (srow > SS - 1 ? SS - 1 : srow);
        short8 kv = *(const short8*)(Kb + (size_t)srow * HDD + dim8);
        short8 vv = *(const short8*)(Vb + (size_t)srow * HDD + dim8);
        *(short8*)&Ks[row8 * 72 + dim8] = kv;
        #pragma unroll
        for (int j = 0; j < 8; j++) Vt[(dim8 + j) * 40 + row8] = vv[j];
        __syncthreads();

        short8 kA0 = *(short8*)&Ks[col * 72 + quad * 8];
        short8 kA1 = *(short8*)&Ks[col * 72 + 32 + quad * 8];
        short8 kB0 = *(short8*)&Ks[(16 + col) * 72 + quad * 8];
        short8 kB1 = *(short8*)&Ks[(16 + col) * 72 + 32 + quad * 8];
        float4v sA = {0,0,0,0}, sB = {0,0,0,0};
        sA = __builtin_amdgcn_mfma_f32_16x16x32_bf16(qf0, kA0, sA, 0, 0, 0);
        sA = __builtin_amdgcn_mfma_f32_16x16x32_bf16(qf1, kA1, sA, 0, 0, 0);
        sB = __builtin_amdgcn_mfma_f32_16x16x32_bf16(qf0, kB0, sB, 0, 0, 0);
        sB = __builtin_amdgcn_mfma_f32_16x16x32_bf16(qf1, kB1, sB, 0, 0, 0);

        #pragma unroll
        for (int r = 0; r < 4; r++) {
            int q  = 16 * w + quad * 4 + r;
            int qq = qq0 + q;
            bool vA, vB;
            if (c < 18) {
                int jA = ch0 + col, jB = jA + 16;
                int dA = jA - qq; dA = dA < 0 ? -dA : dA;
                int dB = jB - qq; dB = dB < 0 ? -dB : dB;
                vA = (jA >= 0) && (jA < 1024) && (dA <= 256);
                vB = (jB >= 0) && (jB < 1024) && (dB <= 256);
            } else {
                int i = 2 * qq + p;
                int jA = gjs[col], jB = gjs[col + 16];
                int dA = jA - i, dB = jB - i;
                int aA = dA < 0 ? -dA : dA;
                int aB = dB < 0 ? -dB : dB;
                vA = (jA >= 0) && !((aA <= 512) && ((dA & 1) == 0));
                vB = (jB >= 0) && !((aB <= 512) && ((dB & 1) == 0));
            }
            float pa = vA ? __expf(sA[r] * 0.125f) : 0.f;
            float pb = vB ? __expf(sB[r] * 0.125f) : 0.f;
            lst[r] += pa + pb;
            Ps[(w * 16 + quad * 4 + r) * 40 + col]      = f2bf(pa);
            Ps[(w * 16 + quad * 4 + r) * 40 + col + 16] = f2bf(pb);
        }
        asm volatile("s_waitcnt lgkmcnt(0)" ::: "memory");

        short8 pf  = *(short8*)&Ps[(w * 16 + col) * 40 + quad * 8];
        short8 vf0 = *(short8*)&Vt[(col) * 40 + quad * 8];
        short8 vf1 = *(short8*)&Vt[(16 + col) * 40 + quad * 8];
        short8 vf2 = *(short8*)&Vt[(32 + col) * 40 + quad * 8];
        short8 vf3 = *(short8*)&Vt[(48 + col) * 40 + quad * 8];
        O0 = __builtin_amdgcn_mfma_f32_16x16x32_bf16(pf, vf0, O0, 0, 0, 0);
        O1 = __builtin_amdgcn_mfma_f32_16x16x32_bf16(pf, vf1, O1, 0, 0, 0);
        O2 = __builtin_amdgcn_mfma_f32_16x16x32_bf16(pf, vf2, O2, 0, 0, 0);
        O3 = __builtin_amdgcn_mfma_f32_16x16x32_bf16(pf, vf3, O3, 0, 0, 0);
    }

    #pragma unroll
    for (int r = 0; r < 4; r++) {
        float l = lst[r];
        #pragma unroll
        for (int mk = 1; mk < 16; mk <<= 1) l += __shfl_xor(l, mk);
        float inv = 1.0f / l;
        int q = 16 * w + quad * 4 + r;
        int i = 2 * (qq0 + q) + p;
        short* dst = ao + ((size_t)b * SS + i) * DMM + h * HDD;
        dst[col]      = f2bf(O0[r] * inv);
        dst[col + 16] = f2bf(O1[r] * inv);
        dst[col + 32] = f2bf(O2[r] * inv);
        dst[col + 48] = f2bf(O3[r] * inv);
    }
}

// ---------------- global rows: split-K MFMA partials (no-max softmax) ----------------
__global__ __launch_bounds__(256)
void global_part(const short* __restrict__ qh, const short* __restrict__ kh,
                 const short* __restrict__ vh, const int* __restrict__ glist,
                 const int* __restrict__ gcount,
                 float* __restrict__ pl, float* __restrict__ pO) {
    __shared__ short Qs[32 * 72];
    __shared__ short Ks[2][32 * 72];
    __shared__ short Vt[2][64 * 40];
    __shared__ short Ps[4 * 16 * 40];

    int t = threadIdx.x;
    int s = blockIdx.x, h = blockIdx.y, b = blockIdx.z;
    int nG = *gcount;

    const short* Qb = qh + ((size_t)(b * HH + h) * SS) * HDD;
    const short* Kb = kh + ((size_t)(b * HH + h) * SS) * HDD;
    const short* Vb = vh + ((size_t)(b * HH + h) * SS) * HDD;

    int row8 = t >> 3, dim8 = (t & 7) * 8;
    {
        int cq = row8 < nG ? row8 : 0;
        int src = glist[cq];
        short8 qv = *(const short8*)(Qb + (size_t)src * HDD + dim8);
        *(short8*)&Qs[row8 * 72 + dim8] = qv;
    }
    __syncthreads();

    int lane = t & 63, w = t >> 6;
    int quad = lane >> 4, col = lane & 15;
    int g = w >> 1, qt = w & 1;

    short8 qf0 = *(short8*)&Qs[(qt * 16 + col) * 72 + quad * 8];
    short8 qf1 = *(short8*)&Qs[(qt * 16 + col) * 72 + 32 + quad * 8];

    float4v O0 = {0,0,0,0}, O1 = {0,0,0,0}, O2 = {0,0,0,0}, O3 = {0,0,0,0};
    float lst[4] = {0.f, 0.f, 0.f, 0.f};

    int js0 = s * 256;
    for (int it = 0; it < 4; it++) {
        __syncthreads();
        int r64 = t >> 2, dimb = (t & 3) * 16;
        int j = js0 + it * 64 + r64;
        const short* kp = Kb + (size_t)j * HDD + dimb;
        const short* vp = Vb + (size_t)j * HDD + dimb;
        short8 k0 = *(const short8*)kp, k1 = *(const short8*)(kp + 8);
        short8 v0 = *(const short8*)vp, v1 = *(const short8*)(vp + 8);
        int half = r64 >> 5, r32 = r64 & 31;
        *(short8*)&Ks[half][r32 * 72 + dimb]     = k0;
        *(short8*)&Ks[half][r32 * 72 + dimb + 8] = k1;
        #pragma unroll
        for (int u = 0; u < 8; u++) Vt[half][(dimb + u) * 40 + r32]     = v0[u];
        #pragma unroll
        for (int u = 0; u < 8; u++) Vt[half][(dimb + 8 + u) * 40 + r32] = v1[u];
        __syncthreads();

        short8 kA0 = *(short8*)&Ks[g][col * 72 + quad * 8];
        short8 kA1 = *(short8*)&Ks[g][col * 72 + 32 + quad * 8];
        short8 kB0 = *(short8*)&Ks[g][(16 + col) * 72 + quad * 8];
        short8 kB1 = *(short8*)&Ks[g][(16 + col) * 72 + 32 + quad * 8];
        float4v sA = {0,0,0,0}, sB = {0,0,0,0};
        sA = __builtin_amdgcn_mfma_f32_16x16x32_bf16(qf0, kA0, sA, 0, 0, 0);
        sA = __builtin_amdgcn_mfma_f32_16x16x32_bf16(qf1, kA1, sA, 0, 0, 0);
        sB = __builtin_amdgcn_mfma_f32_16x16x32_bf16(qf0, kB0, sB, 0, 0, 0);
        sB = __builtin_amdgcn_mfma_f32_16x16x32_bf16(qf1, kB1, sB, 0, 0, 0);

        #pragma unroll
        for (int r = 0; r < 4; r++) {
            float pa = __expf(sA[r] * 0.125f);
            float pb = __expf(sB[r] * 0.125f);
            lst[r] += pa + pb;
            Ps[(w * 16 + quad * 4 + r) * 40 + col]      = f2bf(pa);
            Ps[(w * 16 + quad * 4 + r) * 40 + col + 16] = f2bf(pb);
        }
        asm volatile("s_waitcnt lgkmcnt(0)" ::: "memory");

        short8 pf  = *(short8*)&Ps[(w * 16 + col) * 40 + quad * 8];
        short8 vf0 = *(short8*)&Vt[g][(col) * 40 + quad * 8];
        short8 vf1 = *(short8*)&Vt[g][(16 + col) * 40 + quad * 8];
        short8 vf2 = *(short8*)&Vt[g][(32 + col) * 40 + quad * 8];
        short8 vf3 = *(short8*)&Vt[g][(48 + col) * 40 + quad * 8];
        O0 = __builtin_amdgcn_mfma_f32_16x16x32_bf16(pf, vf0, O0, 0, 0, 0);
        O1 = __builtin_amdgcn_mfma_f32_16x16x32_bf16(pf, vf1, O1, 0, 0, 0);
        O2 = __builtin_amdgcn_mfma_f32_16x16x32_bf16(pf, vf2, O2, 0, 0, 0);
        O3 = __builtin_amdgcn_mfma_f32_16x16x32_bf16(pf, vf3, O3, 0, 0, 0);
    }

    int sp = s * 2 + g;
    size_t base = ((size_t)(b * HH + h) * 16 + sp) * 32;
    #pragma unroll
    for (int r = 0; r < 4; r++) {
        float l = lst[r];
        #pragma unroll
        for (int mk = 1; mk < 16; mk <<= 1) l += __shfl_xor(l, mk);
        int q = qt * 16 + quad * 4 + r;
        if (col == 0) pl[base + q] = l;
        float* Od = pO + (base + q) * 64;
        Od[col]      = O0[r];
        Od[col + 16] = O1[r];
        Od[col + 32] = O2[r];
        Od[col + 48] = O3[r];
    }
}

// ---------------- merge 16 partials per (b,h): plain sums ----------------
__global__ __launch_bounds__(256)
void global_merge(const float* __restrict__ pl, const float* __restrict__ pO,
                  const int* __restrict__ glist, const int* __restrict__ gcount,
                  short* __restrict__ ao) {
    int h = blockIdx.x, b = blockIdx.y;
    int t = threadIdx.x;
    int d = t & 63, qg = t >> 6;
    int nG = *gcount;
    size_t bh = ((size_t)(b * HH + h) * 16) * 32;

    for (int q = qg; q < nG; q += 4) {
        float L = 0.f, acc = 0.f;
        #pragma unroll
        for (int sp = 0; sp < 16; sp++) {
            L   += pl[bh + sp * 32 + q];
            acc += pO[(bh + sp * 32 + q) * 64 + d];
        }
        int i = glist[q];
        ao[((size_t)b * SS + i) * DMM + h * HDD + d] = f2bf(acc / L);
    }
}

extern "C" void kernel_launch(void* const* d_in, const int* in_sizes, int n_in,
                              void* d_out, int out_size, void* d_ws, size_t ws_size,
                              hipStream_t stream) {
    const float* q  = (const float*)d_in[0];
    const float* k  = (const float*)d_in[1];
    const float* v  = (const float*)d_in[2];
    const float* Wq = (const float*)d_in[3];
    const float* Wk = (const float*)d_in[4];
    const float* Wv = (const float*)d_in[5];
    const float* Wo = (const float*)d_in[6];
    const float* bq = (const float*)d_in[7];
    const float* bk = (const float*)d_in[8];
    const float* bv = (const float*)d_in[9];
    const float* bo = (const float*)d_in[10];
    const int* gidx = (const int*)d_in[11];
    float* out = (float*)d_out;

    // ws: 32KB hdr | qh,kh,vh,ao bf16 8MB ea | pl 64KB | pO 4MB | Wbf16 2MB x4
    const size_t NE = (size_t)BB * SS * DMM;
    const size_t WE = (size_t)DMM * DMM;
    int*   g      = (int*)d_ws;
    int*   glist  = g + SS;
    int*   gcount = glist + SS;
    short* qh     = (short*)((char*)d_ws + 32768);
    short* kh     = qh + NE;
    short* vh     = kh + NE;
    short* ao     = vh + NE;
    float* pl     = (float*)(ao + NE);
    float* pO     = pl + 16384;
    short* wbf    = (short*)(pO + 16384 * 64);
    short* wo     = wbf + 3 * WE;

    setup_globals<<<1, 256, 0, stream>>>(gidx, g, glist, gcount);

    dim3 gc(512, 4);
    convert_w<<<gc, 256, 0, stream>>>(Wq, Wk, Wv, Wo, wbf);

    // batched QKV projection: one dispatch, z selects matrix
    dim3 gq(512, 3);
    gemm_mfma<0,1,1><<<gq, 256, 0, stream>>>(q, k, v, wbf, bq, bk, bv, qh, kh, vh);

    dim3 ga(16, HH, BB * 2);
    band_attn<<<ga, 256, 0, stream>>>(qh, kh, vh, glist, gcount, ao);

    dim3 gp(8, HH, BB);
    global_part<<<gp, 256, 0, stream>>>(qh, kh, vh, glist, gcount, pl, pO);

    dim3 gm(HH, BB);
    global_merge<<<gm, 256, 0, stream>>>(pl, pO, glist, gcount, ao);

    dim3 go(512, 1);
    gemm_mfma<1,0,0><<<go, 256, 0, stream>>>(ao, ao, ao, wo, bo, bo, bo, out, out, out);
}